// Round 18
// baseline (2759.974 us; speedup 1.0000x reference)
//
#include <hip/hip_runtime.h>
#include <math.h>

namespace {

constexpr int NB  = 256;
constexpr int NT  = 20;
constexpr int NR  = 100;
constexpr int IND = 300;
constexpr int NH  = 1024;
constexpr int VD  = 2048;
constexpr int H4  = 4096;
constexpr int VOC = 10000;
constexpr int VOCP = 10112;   // vocab padded to 128

// ALL activations and weights plain bf16-hi (1-slot), rows swizzled by
// Frow(row&15)<<3 on the 8-elem slot index (gload-linear LDS + XOR read).
constexpr int KGV = 2368;     // gates_v: hc1024 + hv1024 + x300 -> pad 2368
constexpr int KGC = 4096;     // gates_c: feat2048 + hv1024 + hc1024
constexpr int KHA = 1024;
constexpr int KCL = 1024;     // classifier (1-slot both sides)
constexpr int KFM = 2048;     // FMG/VINP from FM16
constexpr int NVI = 384;      // VINP N padded to 3*128
constexpr int A2VLD = 2048;   // A2v row: [h_c(1024) | h_v(1024)]; x-seg from X2
constexpr int X2LD  = 320;    // 300 payload + 20 zero pad

// gates GEMMs: BM=256 (B staged ONCE), BN=64, Z=8 -> 512 blocks (2/CU),
// 16 MFMA/wave per barrier (2x the BM=128 ratio).
constexpr int ZGV = 8;  constexpr int KSV = 320;   // 7x320 + 128 = 2368
constexpr int ZGC = 8;  constexpr int KSC = 512;
constexpr int ZHA = 8;  constexpr int KSH = 128;
constexpr int ZFM = 8;  constexpr int KSF = 256;   // setup (BM=128, BN=128)

typedef short  s8v  __attribute__((ext_vector_type(8)));
typedef float  f4v  __attribute__((ext_vector_type(4)));

__device__ __forceinline__ float sigm(float x) { return 1.f / (1.f + expf(-x)); }
__device__ __forceinline__ unsigned short f2b(float x) {
  return __builtin_bit_cast(unsigned short, (__bf16)x);
}
__device__ __forceinline__ float b2f(unsigned short u) {
  return (float)__builtin_bit_cast(__bf16, u);
}
__device__ __forceinline__ int Frow(int row) { return (row ^ (row >> 2)) & 3; }
__device__ __forceinline__ void store1(unsigned short* rowbase, int k, float x, int Fs) {
  rowbase[k ^ Fs] = f2b(x);
}

__device__ __forceinline__ void gload16(const unsigned short* g, unsigned short* l) {
  __builtin_amdgcn_global_load_lds(
      (const __attribute__((address_space(1))) void*)g,
      (__attribute__((address_space(3))) void*)l, 16, 0, 0);
}

#define BARRIER()  __syncthreads()
#define VMWAIT0()  asm volatile("s_waitcnt vmcnt(0)" ::: "memory")

// =================== 128x128 bf16 MFMA GEMM, 2-phase dbuf (plain A+B) ===========
template<bool OUT_BF16>
__global__ __launch_bounds__(256)
void gemm128(const unsigned short* __restrict__ A, int lda,
             const unsigned short* __restrict__ Bt, int ldb,
             void* __restrict__ Cv, int ldc,
             const float* __restrict__ bias,
             int N, int Kp)
{
  __shared__ unsigned short As[2][128 * 32];
  __shared__ unsigned short Bs[2][128 * 32];
  const int tid = threadIdx.x, wid = tid >> 6, lane = tid & 63;
  const int wm = (wid >> 1) * 64, wn = (wid & 1) * 64;
  const int m0 = blockIdx.x * 128, n0 = blockIdx.y * 128;
  const int sr = tid >> 2, sc = (tid & 3) * 8;
  const unsigned short* a0 = A + (size_t)(m0 + sr) * lda + sc;
  const unsigned short* a1 = a0 + (size_t)64 * lda;
  const unsigned short* b0 = Bt + (size_t)(n0 + sr) * ldb + sc;
  const unsigned short* b1 = b0 + (size_t)64 * ldb;
  const int rr = lane & 15;
  const int kc = (((lane >> 4) ^ Frow(rr)) & 3) * 8;

  f4v acc[4][4] = {};

  auto stage = [&](int s, int k) {
    gload16(a0 + k, &As[s][tid * 8]);
    gload16(a1 + k, &As[s][2048 + tid * 8]);
    gload16(b0 + k, &Bs[s][tid * 8]);
    gload16(b1 + k, &Bs[s][2048 + tid * 8]);
  };
  auto compute = [&](int s) {
    s8v b[4];
#pragma unroll
    for (int j = 0; j < 4; ++j) b[j] = *(const s8v*)&Bs[s][(wn + j * 16 + rr) * 32 + kc];
#pragma unroll
    for (int i = 0; i < 4; ++i) {
      const s8v av = *(const s8v*)&As[s][(wm + i * 16 + rr) * 32 + kc];
#pragma unroll
      for (int j = 0; j < 4; ++j)
        acc[i][j] = __builtin_amdgcn_mfma_f32_16x16x32_bf16(av, b[j], acc[i][j], 0, 0, 0);
    }
  };

  stage(0, 0);
  VMWAIT0();
  BARRIER();

  int cur = 0;
  for (int k0 = 0; k0 < Kp; k0 += 32) {
    if (k0 + 32 < Kp) stage(cur ^ 1, k0 + 32);
    compute(cur);
    VMWAIT0();
    BARRIER();
    cur ^= 1;
  }

  const int cr = (lane >> 4) * 4, cc = lane & 15;
#pragma unroll
  for (int i = 0; i < 4; ++i) {
#pragma unroll
    for (int j = 0; j < 4; ++j) {
      const int gn = n0 + wn + j * 16 + cc;
      if (gn >= N) continue;
#pragma unroll
      for (int r = 0; r < 4; ++r) {
        const int gm = m0 + wm + i * 16 + cr + r;
        float v = acc[i][j][r] + bias[gn];
        if constexpr (OUT_BF16) ((unsigned short*)Cv)[(size_t)gm * ldc + gn] = f2b(v);
        else                    ((float*)Cv)[(size_t)gm * ldc + gn] = v;
      }
    }
  }
}

// ========= split-K GEMM, BM/BN templated; 4 waves as 2m x 2n ====================
// BM=256: B staged once per (n,z) block; per-i A-frag load keeps VGPR low.
template<bool XSEG, int BM, int BN>
__global__ __launch_bounds__(256)
void gemm_sk2(const unsigned short* __restrict__ A, int lda,
              const unsigned short* __restrict__ X2, int t,
              const unsigned short* __restrict__ Bt, int ldb,
              float* __restrict__ P, int N, int Kp, int Ksplit)
{
  constexpr int FM = BM / 32;     // A fragments per wave
  constexpr int FN = BN / 32;     // B fragments per wave
  constexpr int AG = BM / 64;     // 64-row staging groups
  __shared__ unsigned short As[2][BM * 32];
  __shared__ unsigned short Bs[2][BN * 32];
  const int tid = threadIdx.x, wid = tid >> 6, lane = tid & 63;
  const int wm = (wid >> 1) * (BM / 2), wn = (wid & 1) * (BN / 2);
  const int m0 = blockIdx.y * BM, n0 = blockIdx.x * BN;
  const int kbeg = blockIdx.z * Ksplit;
  const int kend = min(Kp, kbeg + Ksplit);
  const int sr = tid >> 2, sc = (tid & 3) * 8;

  const unsigned short* ap[AG];
  const unsigned short* xp[AG];
#pragma unroll
  for (int g = 0; g < AG; ++g) {
    ap[g] = A + (size_t)(m0 + sr + 64 * g) * lda + sc;
    if constexpr (XSEG)
      xp[g] = X2 + ((size_t)(m0 + sr + 64 * g) * NT + t) * X2LD + sc;
  }
  const unsigned short* b0 = Bt + (size_t)(n0 + sr) * ldb + sc;
  const unsigned short* b1 = b0 + (size_t)64 * ldb;   // BN==128 only
  const int rr = lane & 15;
  const int kc = (((lane >> 4) ^ Frow(rr)) & 3) * 8;

  f4v acc[FM][FN] = {};

  auto stage = [&](int s, int k) {
    if constexpr (XSEG) {
      if (k >= A2VLD) {
#pragma unroll
        for (int g = 0; g < AG; ++g)
          gload16(xp[g] + (k - A2VLD), &As[s][g * 2048 + tid * 8]);
      } else {
#pragma unroll
        for (int g = 0; g < AG; ++g)
          gload16(ap[g] + k, &As[s][g * 2048 + tid * 8]);
      }
    } else {
#pragma unroll
      for (int g = 0; g < AG; ++g)
        gload16(ap[g] + k, &As[s][g * 2048 + tid * 8]);
    }
    gload16(b0 + k, &Bs[s][tid * 8]);
    if constexpr (BN == 128) gload16(b1 + k, &Bs[s][2048 + tid * 8]);
  };
  auto compute = [&](int s) {
    s8v b[FN];
#pragma unroll
    for (int j = 0; j < FN; ++j) b[j] = *(const s8v*)&Bs[s][(wn + j * 16 + rr) * 32 + kc];
#pragma unroll
    for (int i = 0; i < FM; ++i) {
      const s8v av = *(const s8v*)&As[s][(wm + i * 16 + rr) * 32 + kc];
#pragma unroll
      for (int j = 0; j < FN; ++j)
        acc[i][j] = __builtin_amdgcn_mfma_f32_16x16x32_bf16(av, b[j], acc[i][j], 0, 0, 0);
    }
  };

  stage(0, kbeg);
  VMWAIT0();
  BARRIER();

  int cur = 0;
  for (int k0 = kbeg; k0 < kend; k0 += 32) {
    if (k0 + 32 < kend) stage(cur ^ 1, k0 + 32);
    compute(cur);
    VMWAIT0();
    BARRIER();
    cur ^= 1;
  }

  float* out = P + (size_t)blockIdx.z * 256 * N;
  const int cr = (lane >> 4) * 4, cc = lane & 15;
#pragma unroll
  for (int i = 0; i < FM; ++i)
#pragma unroll
    for (int j = 0; j < FN; ++j)
#pragma unroll
      for (int r = 0; r < 4; ++r)
        out[(size_t)(m0 + wm + i * 16 + cr + r) * N + n0 + wn + j * 16 + cc] = acc[i][j][r];
}

// =================== 128x128 VA fallback (fp32 A converted on stage) ============
__global__ __launch_bounds__(256)
void gemm_va_f32(const float* __restrict__ A, int lda,
                 const unsigned short* __restrict__ Bt, int ldb,
                 unsigned short* __restrict__ C, int ldc,
                 const float* __restrict__ bias, int N, int Kp)
{
  __shared__ unsigned short As[128 * 32];
  __shared__ unsigned short Bs[128 * 32];
  const int tid = threadIdx.x, wid = tid >> 6, lane = tid & 63;
  const int wm = (wid >> 1) * 64, wn = (wid & 1) * 64;
  const int m0 = blockIdx.x * 128, n0 = blockIdx.y * 128;
  const unsigned short* bsrc0 = Bt + (size_t)(n0 + (tid >> 2)) * ldb + (tid & 3) * 8;
  const unsigned short* bsrc1 = bsrc0 + (size_t)64 * ldb;
  const int rr = lane & 15;
  const int kc = (((lane >> 4) ^ Frow(rr)) & 3) * 8;

  f4v acc[4][4] = {};
  for (int k0 = 0; k0 < Kp; k0 += 32) {
#pragma unroll
    for (int it = 0; it < 4; ++it) {
      const int r = it * 32 + (tid >> 3), c = (tid & 7) * 4;
      const float4 v = *(const float4*)(A + (size_t)(m0 + r) * lda + k0 + c);
      ushort4 w;
      w.x = f2b(v.x); w.y = f2b(v.y); w.z = f2b(v.z); w.w = f2b(v.w);
      *(ushort4*)&As[r * 32 + (c ^ (Frow(r & 15) << 3))] = w;
    }
    gload16(bsrc0 + k0, &Bs[tid * 8]);
    gload16(bsrc1 + k0, &Bs[2048 + tid * 8]);
    __syncthreads();
    s8v a[4], b[4];
#pragma unroll
    for (int i = 0; i < 4; ++i) a[i] = *(const s8v*)&As[(wm + i * 16 + rr) * 32 + kc];
#pragma unroll
    for (int j = 0; j < 4; ++j) b[j] = *(const s8v*)&Bs[(wn + j * 16 + rr) * 32 + kc];
#pragma unroll
    for (int i = 0; i < 4; ++i)
#pragma unroll
      for (int j = 0; j < 4; ++j)
        acc[i][j] = __builtin_amdgcn_mfma_f32_16x16x32_bf16(a[i], b[j], acc[i][j], 0, 0, 0);
    __syncthreads();
  }
  const int cr = (lane >> 4) * 4, cc = lane & 15;
#pragma unroll
  for (int i = 0; i < 4; ++i)
#pragma unroll
    for (int j = 0; j < 4; ++j) {
      const int gn = n0 + wn + j * 16 + cc;
      if (gn >= N) continue;
#pragma unroll
      for (int r = 0; r < 4; ++r)
        C[(size_t)(m0 + wm + i * 16 + cr + r) * ldc + gn] = f2b(acc[i][j][r] + bias[gn]);
    }
}

// =================== weight transpose+convert (swizzled bf16-hi) ================
__global__ void convB_k(const float* __restrict__ src, int srcld, int K, int N,
                        unsigned short* __restrict__ dst, int dstld, int coff)
{
  __shared__ float t[32][33];
  const int kb = blockIdx.x * 32, nb = blockIdx.y * 32;
  const int tx = threadIdx.x & 31, ty = threadIdx.x >> 5;
#pragma unroll
  for (int i = 0; i < 32; i += 8) {
    const int k = kb + ty + i, n = nb + tx;
    t[ty + i][tx] = (k < K && n < N) ? src[(size_t)k * srcld + n] : 0.f;
  }
  __syncthreads();
#pragma unroll
  for (int i = 0; i < 32; i += 8) {
    const int n = nb + ty + i, k = kb + tx;
    if (n >= N || k >= K) continue;
    unsigned short* row = dst + (size_t)n * dstld;
    row[(coff + k) ^ (Frow(n & 15) << 3)] = f2b(t[tx][ty + i]);
  }
}

// zero swizzled columns [c0, ld)
__global__ void zpad_swz_k(unsigned short* __restrict__ dst, int ld, int c0, int N)
{
  const int w = ld - c0;
  const int idx = blockIdx.x * 256 + threadIdx.x;
  if (idx >= N * w) return;
  const int n = idx / w, c = c0 + (idx % w);
  dst[(size_t)n * ld + (c ^ (Frow(n & 15) << 3))] = 0;
}

__global__ void zfill_k(unsigned short* __restrict__ p, int n)
{
  const int i = blockIdx.x * 256 + threadIdx.x;
  if (i < n) p[i] = 0;
}

// ============ fused feature pass: mean(bf16 swizzled) + feat bf16 convert =======
__global__ void feat_pass_k(const float* __restrict__ feat,
                            unsigned short* __restrict__ fm16,
                            unsigned short* __restrict__ f16out)
{
  const int idx = blockIdx.x * 256 + threadIdx.x;   // NB * VD/8
  if (idx >= NB * (VD / 8)) return;
  const int d0 = (idx & (VD / 8 - 1)) * 8, b = idx / (VD / 8);
  const float* base = feat + (size_t)b * NR * VD + d0;
  float s[8] = {};
  for (int r = 0; r < NR; ++r) {
    const float4 x0 = *(const float4*)(base + (size_t)r * VD);
    const float4 x1 = *(const float4*)(base + (size_t)r * VD + 4);
    s[0] += x0.x; s[1] += x0.y; s[2] += x0.z; s[3] += x0.w;
    s[4] += x1.x; s[5] += x1.y; s[6] += x1.z; s[7] += x1.w;
    if (f16out) {
      unsigned short w[8] = {f2b(x0.x), f2b(x0.y), f2b(x0.z), f2b(x0.w),
                             f2b(x1.x), f2b(x1.y), f2b(x1.z), f2b(x1.w)};
      const int ro = b * NR + r;
      *(s8v*)(f16out + (size_t)ro * VD + (d0 ^ (Frow(ro & 15) << 3))) = *(const s8v*)w;
    }
  }
  unsigned short w[8];
#pragma unroll
  for (int e = 0; e < 8; ++e) w[e] = f2b(s[e] * (1.f / NR));
  *(s8v*)(fm16 + (size_t)b * KFM + (d0 ^ (Frow(b & 15) << 3))) = *(const s8v*)w;
}

// FMG = b_v + sum_z GP[z]
__global__ void fmg_red_k(const float* __restrict__ gp, const float* __restrict__ bv,
                          float* __restrict__ fmg)
{
  const int idx = blockIdx.x * 256 + threadIdx.x;   // NB*H4
  if (idx >= NB * H4) return;
  float s = bv[idx & (H4 - 1)];
#pragma unroll
  for (int z = 0; z < ZFM; ++z) s += gp[(size_t)z * NB * H4 + idx];
  fmg[idx] = s;
}

// VINP = b_vin + sum_z GP[z] (N=NVI partials, keep n<IND)
__global__ void vinp_red_k(const float* __restrict__ gp, const float* __restrict__ bvin,
                           float* __restrict__ vinp)
{
  const int idx = blockIdx.x * 256 + threadIdx.x;   // NB*IND
  if (idx >= NB * IND) return;
  const int n = idx % IND, b = idx / IND;
  float s = bvin[n];
#pragma unroll
  for (int z = 0; z < ZFM; ++z) s += gp[(size_t)z * NB * NVI + (size_t)b * NVI + n];
  vinp[idx] = s;
}

// X2: plain bf16-hi, swizzled by F(b); payload d<300
__global__ void build_x2_k(const int* __restrict__ cap, const float* __restrict__ emb,
                           const float* __restrict__ vinp, unsigned short* __restrict__ X2)
{
  const int idx = blockIdx.x * 256 + threadIdx.x;
  if (idx >= NB * NT * X2LD) return;
  const int c = idx % X2LD;
  const int bt = idx / X2LD;
  const int t = bt % NT, b = bt / NT;
  const int Fs = Frow(b & 15) << 3;
  unsigned short val = 0;
  if (c < IND) {
    const float v = (t == 0) ? vinp[b * IND + c]
                             : emb[(size_t)cap[b * (NT - 1) + (t - 1)] * IND + c];
    val = f2b(v);
  }
  X2[(size_t)bt * X2LD + (c ^ Fs)] = val;
}

__global__ void lstm_pw_v_k(const float* __restrict__ gp, const float* __restrict__ fmg,
                            float* __restrict__ cv,
                            unsigned short* __restrict__ A2c, unsigned short* __restrict__ A2v)
{
  const int idx = blockIdx.x * 256 + threadIdx.x;
  if (idx >= NB * NH) return;
  const int n = idx & (NH - 1), b = idx >> 10;
  const size_t base = (size_t)b * H4;
  float gi = fmg[base + n], gf = fmg[base + NH + n];
  float gg = fmg[base + 2 * NH + n], go = fmg[base + 3 * NH + n];
#pragma unroll
  for (int z = 0; z < ZGV; ++z) {
    const float* g = gp + (size_t)z * NB * H4 + base;
    gi += g[n]; gf += g[NH + n]; gg += g[2 * NH + n]; go += g[3 * NH + n];
  }
  const float c2 = sigm(gf) * cv[idx] + sigm(gi) * tanhf(gg);
  const float h2 = sigm(go) * tanhf(c2);
  cv[idx] = c2;
  const int Fs = Frow(b & 15) << 3;
  store1(A2c + (size_t)b * KGC, 2048 + n, h2, Fs);
  store1(A2v + (size_t)b * A2VLD, 1024 + n, h2, Fs);
}

__global__ void lstm_pw_c_k(const float* __restrict__ gp, const float* __restrict__ bc,
                            float* __restrict__ cc,
                            unsigned short* __restrict__ A2v, unsigned short* __restrict__ A2c,
                            unsigned short* __restrict__ outh2, int t)
{
  const int idx = blockIdx.x * 256 + threadIdx.x;
  if (idx >= NB * NH) return;
  const int n = idx & (NH - 1), b = idx >> 10;
  const size_t base = (size_t)b * H4;
  float gi = bc[n], gf = bc[NH + n], gg = bc[2 * NH + n], go = bc[3 * NH + n];
#pragma unroll
  for (int z = 0; z < ZGC; ++z) {
    const float* g = gp + (size_t)z * NB * H4 + base;
    gi += g[n]; gf += g[NH + n]; gg += g[2 * NH + n]; go += g[3 * NH + n];
  }
  const float c2 = sigm(gf) * cc[idx] + sigm(gi) * tanhf(gg);
  const float h2 = sigm(go) * tanhf(c2);
  cc[idx] = c2;
  const int Fs = Frow(b & 15) << 3;
  store1(A2v + (size_t)b * A2VLD, n, h2, Fs);
  store1(A2c + (size_t)b * KGC, 3072 + n, h2, Fs);
  const int ro = b * NT + t;
  store1(outh2 + (size_t)ro * KCL, n, h2, Frow(ro & 15) << 3);
}

// =================== fused attention: ha-reduce + logits + softmax + feat_hat ===
template<bool F16>
__global__ __launch_bounds__(512)
void att_fused_k(const unsigned short* __restrict__ va16,
                 const float* __restrict__ hap,   // [ZHA][NB][NH]
                 const float* __restrict__ bha,
                 const float* __restrict__ Wa, const float* __restrict__ ba,
                 const unsigned short* __restrict__ f16,
                 const float* __restrict__ f32,
                 unsigned short* __restrict__ A2c,
                 float* __restrict__ att_out, int t)
{
  const int b = blockIdx.x, tid = threadIdx.x;
  const int lane = tid & 63, wid = tid >> 6;
  __shared__ float ha_s[NH];
  __shared__ float wa_s[NH];
  __shared__ float red_s[128];
  __shared__ float fh_s[2][VD];

  for (int j = tid; j < NH; j += 512) {
    float s = bha[j];
#pragma unroll
    for (int z = 0; z < ZHA; ++z) s += hap[((size_t)z * NB + b) * NH + j];
    ha_s[j] = s;
    wa_s[j] = Wa[j];
  }
  __syncthreads();

  for (int r = wid; r < NR; r += 8) {
    const unsigned short* vrow = va16 + ((size_t)b * NR + r) * NH + lane * 16;
    float s = 0.f;
#pragma unroll
    for (int u = 0; u < 2; ++u) {
      const s8v v = *(const s8v*)(vrow + u * 8);
      const int j0 = lane * 16 + u * 8;
#pragma unroll
      for (int e = 0; e < 8; ++e)
        s += tanhf(b2f((unsigned short)v[e]) + ha_s[j0 + e]) * wa_s[j0 + e];
    }
    for (int o = 32; o; o >>= 1) s += __shfl_down(s, o);
    if (lane == 0) red_s[r] = s + ba[0];
  }
  __syncthreads();

  if (wid == 0) {
    float v0 = (lane < NR) ? red_s[lane] : -3.4e38f;
    float v1 = (lane + 64 < NR) ? red_s[lane + 64] : -3.4e38f;
    float m = fmaxf(v0, v1);
    for (int o = 32; o; o >>= 1) m = fmaxf(m, __shfl_xor(m, o));
    const float e0 = (lane < NR) ? expf(v0 - m) : 0.f;
    const float e1 = (lane + 64 < NR) ? expf(v1 - m) : 0.f;
    float s = e0 + e1;
    for (int o = 32; o; o >>= 1) s += __shfl_xor(s, o);
    const float inv = 1.f / s;
    if (lane < NR) red_s[lane] = e0 * inv;
    if (lane + 64 < NR) red_s[lane + 64] = e1 * inv;
  }
  __syncthreads();
  if (tid < NR) att_out[((size_t)b * NT + t) * NR + tid] = red_s[tid];

  // feat_hat: split rows across 2 thread-halves; 8 d's (16B) per thread
  const int half = tid >> 8;
  const int dd = (tid & 255) * 8;
  const int r0 = half * 50, r1 = r0 + 50;
  float fh8[8] = {};
  if constexpr (F16) {
    const unsigned short* fbase = f16 + (size_t)b * NR * VD;
    for (int r = r0; r < r1; ++r) {
      const int ro = b * NR + r;
      const s8v f = *(const s8v*)(fbase + (size_t)r * VD + (dd ^ (Frow(ro & 15) << 3)));
      const float a = red_s[r];
#pragma unroll
      for (int e = 0; e < 8; ++e) fh8[e] += a * b2f((unsigned short)f[e]);
    }
  } else {
    const float* fb = f32 + (size_t)b * NR * VD + dd;
    for (int r = r0; r < r1; ++r) {
      const float4 x0 = *(const float4*)(fb + (size_t)r * VD);
      const float4 x1 = *(const float4*)(fb + (size_t)r * VD + 4);
      const float a = red_s[r];
      fh8[0] += a * x0.x; fh8[1] += a * x0.y; fh8[2] += a * x0.z; fh8[3] += a * x0.w;
      fh8[4] += a * x1.x; fh8[5] += a * x1.y; fh8[6] += a * x1.z; fh8[7] += a * x1.w;
    }
  }
#pragma unroll
  for (int e = 0; e < 8; ++e) fh_s[half][dd + e] = fh8[e];
  __syncthreads();

  unsigned short* rowbase = A2c + (size_t)b * KGC;
  const int Fs = Frow(b & 15) << 3;
  const int d0 = tid * 4;
#pragma unroll
  for (int e = 0; e < 4; ++e) {
    const float v = (fh_s[0][d0 + e] + fh_s[1][d0 + e]) * (1.f / NR);
    store1(rowbase, d0 + e, v, Fs);
  }
}

inline void convB(hipStream_t st, const float* src, int srcld, int K, int N,
                  unsigned short* dst, int dstld, int coff)
{
  dim3 g((K + 31) / 32, (N + 31) / 32);
  convB_k<<<g, 256, 0, st>>>(src, srcld, K, N, dst, dstld, coff);
}

} // namespace

extern "C" void kernel_launch(void* const* d_in, const int* in_sizes, int n_in,
                              void* d_out, int out_size, void* d_ws, size_t ws_size,
                              hipStream_t stream)
{
  const int*   caption = (const int*)  d_in[0];
  const float* feat    = (const float*)d_in[1];
  const float* emb     = (const float*)d_in[2];
  const float* W_vin   = (const float*)d_in[3];
  const float* b_vin   = (const float*)d_in[4];
  const float* W_ih_v  = (const float*)d_in[5];
  const float* W_hh_v  = (const float*)d_in[6];
  const float* b_v     = (const float*)d_in[7];
  const float* W_va    = (const float*)d_in[8];
  const float* b_va    = (const float*)d_in[9];
  const float* W_ha    = (const float*)d_in[10];
  const float* b_ha    = (const float*)d_in[11];
  const float* W_a     = (const float*)d_in[12];
  const float* b_a     = (const float*)d_in[13];
  const float* W_ih_c  = (const float*)d_in[14];
  const float* W_hh_c  = (const float*)d_in[15];
  const float* b_c     = (const float*)d_in[16];
  const float* W_cls   = (const float*)d_in[17];
  const float* b_cls   = (const float*)d_in[18];

  float* out_repr = (float*)d_out;                       // [NB,NT,VOC]
  float* out_att  = out_repr + (size_t)NB * NT * VOC;    // [NB,NT,NR]

  char* cur = (char*)d_ws;
  auto take = [&](size_t bytes) { char* p = cur; cur += bytes; return p; };

  unsigned short* A2v  = (unsigned short*)take((size_t)NB * A2VLD * 2);      // 1MB
  unsigned short* A2c  = (unsigned short*)take((size_t)NB * KGC * 2);        // 2MB
  float* CV            = (float*)take((size_t)NB * NH * 4);
  float* CC            = (float*)take((size_t)NB * NH * 4);
  const size_t ZERO_BYTES = (size_t)NB * A2VLD * 2 + (size_t)NB * KGC * 2
                          + 2 * (size_t)NB * NH * 4;

  float* VINP          = (float*)take((size_t)NB * IND * 4);
  unsigned short* X2   = (unsigned short*)take((size_t)NB * NT * X2LD * 2);  // 3.3MB
  float* FMG           = (float*)take((size_t)NB * H4 * 4);
  unsigned short* FM16 = (unsigned short*)take((size_t)NB * KFM * 2);        // 1MB
  unsigned short* VA16 = (unsigned short*)take((size_t)NB * NR * NH * 2);    // 52MB
  float* GP            = (float*)take((size_t)8 * NB * H4 * 4);              // 33.5MB
  float* HAP           = (float*)take((size_t)ZHA * NB * NH * 4);            // 8.4MB
  unsigned short* OUTH2= (unsigned short*)take((size_t)NB * NT * KCL * 2);   // 10.5MB
  unsigned short* Wgv2t= (unsigned short*)take((size_t)H4 * KGV * 2);        // 19.4MB
  unsigned short* Wha2t= (unsigned short*)take((size_t)NH * KHA * 2);        // 2.1MB
  unsigned short* Wgc2t= (unsigned short*)take((size_t)H4 * KGC * 2);        // 33.5MB
  unsigned short* Wfmg = (unsigned short*)take((size_t)H4 * KFM * 2);        // 16.8MB
  unsigned short* WvinT= (unsigned short*)take((size_t)NVI * KFM * 2);       // 1.6MB
  unsigned short* Wcls2t=(unsigned short*)take((size_t)VOCP * KCL * 2);      // 20.7MB
  unsigned short* Wva16t=(unsigned short*)take((size_t)NH * VD * 2);         // 4.2MB
  unsigned short* FEAT16=(unsigned short*)cur;                               // 105MB optional
  const bool useF16 = ((size_t)(cur - (char*)d_ws) + (size_t)NB * NR * VD * 2) <= ws_size;

  hipMemsetAsync(A2v, 0, ZERO_BYTES, stream);

  // ---- weight conversions (all swizzled bf16-hi) ----
  convB(stream, W_ih_v + (size_t)2048 * H4, H4, 1024, H4, Wgv2t, KGV, 0);
  convB(stream, W_hh_v,                     H4, 1024, H4, Wgv2t, KGV, 1024);
  convB(stream, W_ih_v + (size_t)3072 * H4, H4, 300,  H4, Wgv2t, KGV, 2048);
  zpad_swz_k<<<((H4 * (KGV - 2348)) + 255) / 256, 256, 0, stream>>>(
      Wgv2t, KGV, 2348, H4);
  convB(stream, W_ha, NH, 1024, NH, Wha2t, KHA, 0);
  convB(stream, W_ih_c,                     H4, 2048, H4, Wgc2t, KGC, 0);
  convB(stream, W_ih_c + (size_t)2048 * H4, H4, 1024, H4, Wgc2t, KGC, 2048);
  convB(stream, W_hh_c,                     H4, 1024, H4, Wgc2t, KGC, 3072);
  convB(stream, W_ih_v,                     H4, 2048, H4, Wfmg,  KFM, 0);
  convB(stream, W_vin, IND, 2048, IND, WvinT, KFM, 0);
  zfill_k<<<(((NVI - IND) * KFM) + 255) / 256, 256, 0, stream>>>(
      WvinT + (size_t)IND * KFM, (NVI - IND) * KFM);
  convB(stream, W_cls, VOC, 1024, VOC, Wcls2t, KCL, 0);
  zfill_k<<<(((VOCP - VOC) * KCL) + 255) / 256, 256, 0, stream>>>(
      Wcls2t + (size_t)VOC * KCL, (VOCP - VOC) * KCL);
  convB(stream, W_va, NH, VD, NH, Wva16t, VD, 0);

  // ---- setup ----
  feat_pass_k<<<(NB * (VD / 8) + 255) / 256, 256, 0, stream>>>(
      feat, FM16, useF16 ? FEAT16 : nullptr);
  // VINP via MFMA split-K (BM=128, BN=128, Z=8)
  gemm_sk2<false, 128, 128><<<dim3(NVI / 128, 2, ZFM), 256, 0, stream>>>(
      FM16, KFM, nullptr, 0, WvinT, KFM, GP, NVI, KFM, KSF);
  vinp_red_k<<<(NB * IND + 255) / 256, 256, 0, stream>>>(GP, b_vin, VINP);
  build_x2_k<<<(NB * NT * X2LD + 255) / 256, 256, 0, stream>>>(caption, emb, VINP, X2);
  // FMG via MFMA split-K
  gemm_sk2<false, 128, 128><<<dim3(H4 / 128, 2, ZFM), 256, 0, stream>>>(
      FM16, KFM, nullptr, 0, Wfmg, KFM, GP, H4, KFM, KSF);
  fmg_red_k<<<(NB * H4 + 255) / 256, 256, 0, stream>>>(GP, b_v, FMG);
  if (useF16) {
    dim3 g((NB * NR) / 128, NH / 128);
    gemm128<true><<<g, 256, 0, stream>>>(
        FEAT16, VD, Wva16t, VD, VA16, NH, b_va, NH, VD);
  } else {
    dim3 g((NB * NR) / 128, NH / 128);
    gemm_va_f32<<<g, 256, 0, stream>>>(feat, VD, Wva16t, VD, VA16, NH, b_va, NH, VD);
  }

  // ---- sequential decode ----
  for (int t = 0; t < NT; ++t) {
    // gates_v: BM=256 (B staged once), BN=64, Z=8 -> 512 blocks
    gemm_sk2<true, 256, 64><<<dim3(H4 / 64, 1, ZGV), 256, 0, stream>>>(
        A2v, A2VLD, X2, t, Wgv2t, KGV, GP, H4, KGV, KSV);
    lstm_pw_v_k<<<(NB * NH + 255) / 256, 256, 0, stream>>>(GP, FMG, CV, A2c, A2v);
    // ha: BM=128, BN=64, Z=8 -> 256 blocks
    gemm_sk2<false, 128, 64><<<dim3(NH / 64, 2, ZHA), 256, 0, stream>>>(
        A2c + 2048, KGC, nullptr, 0, Wha2t, KHA, HAP, NH, KHA, KSH);
    if (useF16)
      att_fused_k<true><<<NB, 512, 0, stream>>>(
          VA16, HAP, b_ha, W_a, b_a, FEAT16, nullptr, A2c, out_att, t);
    else
      att_fused_k<false><<<NB, 512, 0, stream>>>(
          VA16, HAP, b_ha, W_a, b_a, nullptr, feat, A2c, out_att, t);
    // gates_c: BM=256, BN=64, Z=8 -> 512 blocks
    gemm_sk2<false, 256, 64><<<dim3(H4 / 64, 1, ZGC), 256, 0, stream>>>(
        A2c, KGC, nullptr, 0, Wgc2t, KGC, GP, H4, KGC, KSC);
    lstm_pw_c_k<<<(NB * NH + 255) / 256, 256, 0, stream>>>(GP, b_c, CC, A2v, A2c, OUTH2, t);
  }

  // ---- classifier: 128x128 tiles, plain bf16 both sides, K=1024 ----
  {
    dim3 g((NB * NT) / 128, VOCP / 128);
    gemm128<false><<<g, 256, 0, stream>>>(
        OUTH2, KCL, Wcls2t, KCL, out_repr, VOC, b_cls, VOC, KCL);
  }
}

// Round 19
// 2736.222 us; speedup vs baseline: 1.0087x; 1.0087x over previous
//
#include <hip/hip_runtime.h>
#include <math.h>

namespace {

constexpr int NB  = 256;
constexpr int NT  = 20;
constexpr int NR  = 100;
constexpr int IND = 300;
constexpr int NH  = 1024;
constexpr int VD  = 2048;
constexpr int H4  = 4096;
constexpr int VOC = 10000;
constexpr int VOCP = 10112;   // vocab padded to 128

// ALL activations and weights plain bf16-hi (1-slot), rows swizzled by
// Frow(row&15)<<3 on the 8-elem slot index (gload-linear LDS + XOR read).
constexpr int KGV = 2368;     // gates_v: hc1024 + hv1024 + x300 -> pad 2368
constexpr int KGC = 4096;     // gates_c: feat2048 + hv1024 + hc1024
constexpr int KHA = 1024;
constexpr int KCL = 1024;     // classifier (1-slot both sides)
constexpr int KFM = 2048;     // FMG/VINP from FM16
constexpr int NVI = 384;      // VINP N padded to 3*128
constexpr int A2VLD = 2048;   // A2v row: [h_c(1024) | h_v(1024)]; x-seg from X2
constexpr int X2LD  = 320;    // 300 payload + 20 zero pad

// R17 best-measured config: gv/gc BM=128, BN=64, Z=4 (512 blocks, 2/CU)
constexpr int ZGV = 4;  constexpr int KSV = 608;   // 3x608 + 544
constexpr int ZGC = 4;  constexpr int KSC = 1024;
constexpr int ZHA = 8;  constexpr int KSH = 128;
constexpr int ZFM = 8;  constexpr int KSF = 256;   // setup (BM=128, BN=128)

typedef short  s8v  __attribute__((ext_vector_type(8)));
typedef float  f4v  __attribute__((ext_vector_type(4)));

__device__ __forceinline__ float sigm(float x) { return 1.f / (1.f + expf(-x)); }
__device__ __forceinline__ unsigned short f2b(float x) {
  return __builtin_bit_cast(unsigned short, (__bf16)x);
}
__device__ __forceinline__ float b2f(unsigned short u) {
  return (float)__builtin_bit_cast(__bf16, u);
}
__device__ __forceinline__ int Frow(int row) { return (row ^ (row >> 2)) & 3; }
__device__ __forceinline__ void store1(unsigned short* rowbase, int k, float x, int Fs) {
  rowbase[k ^ Fs] = f2b(x);
}

__device__ __forceinline__ void gload16(const unsigned short* g, unsigned short* l) {
  __builtin_amdgcn_global_load_lds(
      (const __attribute__((address_space(1))) void*)g,
      (__attribute__((address_space(3))) void*)l, 16, 0, 0);
}

#define BARRIER()  __syncthreads()
#define VMWAIT0()  asm volatile("s_waitcnt vmcnt(0)" ::: "memory")

// =================== 128x128 bf16 MFMA GEMM, 2-phase dbuf (plain A+B) ===========
template<bool OUT_BF16>
__global__ __launch_bounds__(256)
void gemm128(const unsigned short* __restrict__ A, int lda,
             const unsigned short* __restrict__ Bt, int ldb,
             void* __restrict__ Cv, int ldc,
             const float* __restrict__ bias,
             int N, int Kp)
{
  __shared__ unsigned short As[2][128 * 32];
  __shared__ unsigned short Bs[2][128 * 32];
  const int tid = threadIdx.x, wid = tid >> 6, lane = tid & 63;
  const int wm = (wid >> 1) * 64, wn = (wid & 1) * 64;
  const int m0 = blockIdx.x * 128, n0 = blockIdx.y * 128;
  const int sr = tid >> 2, sc = (tid & 3) * 8;
  const unsigned short* a0 = A + (size_t)(m0 + sr) * lda + sc;
  const unsigned short* a1 = a0 + (size_t)64 * lda;
  const unsigned short* b0 = Bt + (size_t)(n0 + sr) * ldb + sc;
  const unsigned short* b1 = b0 + (size_t)64 * ldb;
  const int rr = lane & 15;
  const int kc = (((lane >> 4) ^ Frow(rr)) & 3) * 8;

  f4v acc[4][4] = {};

  auto stage = [&](int s, int k) {
    gload16(a0 + k, &As[s][tid * 8]);
    gload16(a1 + k, &As[s][2048 + tid * 8]);
    gload16(b0 + k, &Bs[s][tid * 8]);
    gload16(b1 + k, &Bs[s][2048 + tid * 8]);
  };
  auto compute = [&](int s) {
    s8v b[4];
#pragma unroll
    for (int j = 0; j < 4; ++j) b[j] = *(const s8v*)&Bs[s][(wn + j * 16 + rr) * 32 + kc];
#pragma unroll
    for (int i = 0; i < 4; ++i) {
      const s8v av = *(const s8v*)&As[s][(wm + i * 16 + rr) * 32 + kc];
#pragma unroll
      for (int j = 0; j < 4; ++j)
        acc[i][j] = __builtin_amdgcn_mfma_f32_16x16x32_bf16(av, b[j], acc[i][j], 0, 0, 0);
    }
  };

  stage(0, 0);
  VMWAIT0();
  BARRIER();

  int cur = 0;
  for (int k0 = 0; k0 < Kp; k0 += 32) {
    if (k0 + 32 < Kp) stage(cur ^ 1, k0 + 32);
    compute(cur);
    VMWAIT0();
    BARRIER();
    cur ^= 1;
  }

  const int cr = (lane >> 4) * 4, cc = lane & 15;
#pragma unroll
  for (int i = 0; i < 4; ++i) {
#pragma unroll
    for (int j = 0; j < 4; ++j) {
      const int gn = n0 + wn + j * 16 + cc;
      if (gn >= N) continue;
#pragma unroll
      for (int r = 0; r < 4; ++r) {
        const int gm = m0 + wm + i * 16 + cr + r;
        float v = acc[i][j][r] + bias[gn];
        if constexpr (OUT_BF16) ((unsigned short*)Cv)[(size_t)gm * ldc + gn] = f2b(v);
        else                    ((float*)Cv)[(size_t)gm * ldc + gn] = v;
      }
    }
  }
}

// ========= split-K GEMM, BM/BN templated; 4 waves as 2m x 2n ====================
template<bool XSEG, int BM, int BN>
__global__ __launch_bounds__(256)
void gemm_sk2(const unsigned short* __restrict__ A, int lda,
              const unsigned short* __restrict__ X2, int t,
              const unsigned short* __restrict__ Bt, int ldb,
              float* __restrict__ P, int N, int Kp, int Ksplit)
{
  constexpr int FM = BM / 32;
  constexpr int FN = BN / 32;
  constexpr int AG = BM / 64;
  __shared__ unsigned short As[2][BM * 32];
  __shared__ unsigned short Bs[2][BN * 32];
  const int tid = threadIdx.x, wid = tid >> 6, lane = tid & 63;
  const int wm = (wid >> 1) * (BM / 2), wn = (wid & 1) * (BN / 2);
  const int m0 = blockIdx.y * BM, n0 = blockIdx.x * BN;
  const int kbeg = blockIdx.z * Ksplit;
  const int kend = min(Kp, kbeg + Ksplit);
  const int sr = tid >> 2, sc = (tid & 3) * 8;

  const unsigned short* ap[AG];
  const unsigned short* xp[AG];
#pragma unroll
  for (int g = 0; g < AG; ++g) {
    ap[g] = A + (size_t)(m0 + sr + 64 * g) * lda + sc;
    if constexpr (XSEG)
      xp[g] = X2 + ((size_t)(m0 + sr + 64 * g) * NT + t) * X2LD + sc;
  }
  const unsigned short* b0 = Bt + (size_t)(n0 + sr) * ldb + sc;
  const unsigned short* b1 = b0 + (size_t)64 * ldb;   // BN==128 only
  const int rr = lane & 15;
  const int kc = (((lane >> 4) ^ Frow(rr)) & 3) * 8;

  f4v acc[FM][FN] = {};

  auto stage = [&](int s, int k) {
    if constexpr (XSEG) {
      if (k >= A2VLD) {
#pragma unroll
        for (int g = 0; g < AG; ++g)
          gload16(xp[g] + (k - A2VLD), &As[s][g * 2048 + tid * 8]);
      } else {
#pragma unroll
        for (int g = 0; g < AG; ++g)
          gload16(ap[g] + k, &As[s][g * 2048 + tid * 8]);
      }
    } else {
#pragma unroll
      for (int g = 0; g < AG; ++g)
        gload16(ap[g] + k, &As[s][g * 2048 + tid * 8]);
    }
    gload16(b0 + k, &Bs[s][tid * 8]);
    if constexpr (BN == 128) gload16(b1 + k, &Bs[s][2048 + tid * 8]);
  };
  auto compute = [&](int s) {
    s8v b[FN];
#pragma unroll
    for (int j = 0; j < FN; ++j) b[j] = *(const s8v*)&Bs[s][(wn + j * 16 + rr) * 32 + kc];
#pragma unroll
    for (int i = 0; i < FM; ++i) {
      const s8v av = *(const s8v*)&As[s][(wm + i * 16 + rr) * 32 + kc];
#pragma unroll
      for (int j = 0; j < FN; ++j)
        acc[i][j] = __builtin_amdgcn_mfma_f32_16x16x32_bf16(av, b[j], acc[i][j], 0, 0, 0);
    }
  };

  stage(0, kbeg);
  VMWAIT0();
  BARRIER();

  int cur = 0;
  for (int k0 = kbeg; k0 < kend; k0 += 32) {
    if (k0 + 32 < kend) stage(cur ^ 1, k0 + 32);
    compute(cur);
    VMWAIT0();
    BARRIER();
    cur ^= 1;
  }

  float* out = P + (size_t)blockIdx.z * 256 * N;
  const int cr = (lane >> 4) * 4, cc = lane & 15;
#pragma unroll
  for (int i = 0; i < FM; ++i)
#pragma unroll
    for (int j = 0; j < FN; ++j)
#pragma unroll
      for (int r = 0; r < 4; ++r)
        out[(size_t)(m0 + wm + i * 16 + cr + r) * N + n0 + wn + j * 16 + cc] = acc[i][j][r];
}

// =================== 128x128 VA fallback (fp32 A converted on stage) ============
__global__ __launch_bounds__(256)
void gemm_va_f32(const float* __restrict__ A, int lda,
                 const unsigned short* __restrict__ Bt, int ldb,
                 unsigned short* __restrict__ C, int ldc,
                 const float* __restrict__ bias, int N, int Kp)
{
  __shared__ unsigned short As[128 * 32];
  __shared__ unsigned short Bs[128 * 32];
  const int tid = threadIdx.x, wid = tid >> 6, lane = tid & 63;
  const int wm = (wid >> 1) * 64, wn = (wid & 1) * 64;
  const int m0 = blockIdx.x * 128, n0 = blockIdx.y * 128;
  const unsigned short* bsrc0 = Bt + (size_t)(n0 + (tid >> 2)) * ldb + (tid & 3) * 8;
  const unsigned short* bsrc1 = bsrc0 + (size_t)64 * ldb;
  const int rr = lane & 15;
  const int kc = (((lane >> 4) ^ Frow(rr)) & 3) * 8;

  f4v acc[4][4] = {};
  for (int k0 = 0; k0 < Kp; k0 += 32) {
#pragma unroll
    for (int it = 0; it < 4; ++it) {
      const int r = it * 32 + (tid >> 3), c = (tid & 7) * 4;
      const float4 v = *(const float4*)(A + (size_t)(m0 + r) * lda + k0 + c);
      ushort4 w;
      w.x = f2b(v.x); w.y = f2b(v.y); w.z = f2b(v.z); w.w = f2b(v.w);
      *(ushort4*)&As[r * 32 + (c ^ (Frow(r & 15) << 3))] = w;
    }
    gload16(bsrc0 + k0, &Bs[tid * 8]);
    gload16(bsrc1 + k0, &Bs[2048 + tid * 8]);
    __syncthreads();
    s8v a[4], b[4];
#pragma unroll
    for (int i = 0; i < 4; ++i) a[i] = *(const s8v*)&As[(wm + i * 16 + rr) * 32 + kc];
#pragma unroll
    for (int j = 0; j < 4; ++j) b[j] = *(const s8v*)&Bs[(wn + j * 16 + rr) * 32 + kc];
#pragma unroll
    for (int i = 0; i < 4; ++i)
#pragma unroll
      for (int j = 0; j < 4; ++j)
        acc[i][j] = __builtin_amdgcn_mfma_f32_16x16x32_bf16(a[i], b[j], acc[i][j], 0, 0, 0);
    __syncthreads();
  }
  const int cr = (lane >> 4) * 4, cc = lane & 15;
#pragma unroll
  for (int i = 0; i < 4; ++i)
#pragma unroll
    for (int j = 0; j < 4; ++j) {
      const int gn = n0 + wn + j * 16 + cc;
      if (gn >= N) continue;
#pragma unroll
      for (int r = 0; r < 4; ++r)
        C[(size_t)(m0 + wm + i * 16 + cr + r) * ldc + gn] = f2b(acc[i][j][r] + bias[gn]);
    }
}

// =================== weight transpose+convert (swizzled bf16-hi) ================
__global__ void convB_k(const float* __restrict__ src, int srcld, int K, int N,
                        unsigned short* __restrict__ dst, int dstld, int coff)
{
  __shared__ float t[32][33];
  const int kb = blockIdx.x * 32, nb = blockIdx.y * 32;
  const int tx = threadIdx.x & 31, ty = threadIdx.x >> 5;
#pragma unroll
  for (int i = 0; i < 32; i += 8) {
    const int k = kb + ty + i, n = nb + tx;
    t[ty + i][tx] = (k < K && n < N) ? src[(size_t)k * srcld + n] : 0.f;
  }
  __syncthreads();
#pragma unroll
  for (int i = 0; i < 32; i += 8) {
    const int n = nb + ty + i, k = kb + tx;
    if (n >= N || k >= K) continue;
    unsigned short* row = dst + (size_t)n * dstld;
    row[(coff + k) ^ (Frow(n & 15) << 3)] = f2b(t[tx][ty + i]);
  }
}

// zero swizzled columns [c0, ld)
__global__ void zpad_swz_k(unsigned short* __restrict__ dst, int ld, int c0, int N)
{
  const int w = ld - c0;
  const int idx = blockIdx.x * 256 + threadIdx.x;
  if (idx >= N * w) return;
  const int n = idx / w, c = c0 + (idx % w);
  dst[(size_t)n * ld + (c ^ (Frow(n & 15) << 3))] = 0;
}

__global__ void zfill_k(unsigned short* __restrict__ p, int n)
{
  const int i = blockIdx.x * 256 + threadIdx.x;
  if (i < n) p[i] = 0;
}

// ============ fused feature pass: mean(bf16 swizzled) + feat bf16 convert =======
__global__ void feat_pass_k(const float* __restrict__ feat,
                            unsigned short* __restrict__ fm16,
                            unsigned short* __restrict__ f16out)
{
  const int idx = blockIdx.x * 256 + threadIdx.x;   // NB * VD/8
  if (idx >= NB * (VD / 8)) return;
  const int d0 = (idx & (VD / 8 - 1)) * 8, b = idx / (VD / 8);
  const float* base = feat + (size_t)b * NR * VD + d0;
  float s[8] = {};
  for (int r = 0; r < NR; ++r) {
    const float4 x0 = *(const float4*)(base + (size_t)r * VD);
    const float4 x1 = *(const float4*)(base + (size_t)r * VD + 4);
    s[0] += x0.x; s[1] += x0.y; s[2] += x0.z; s[3] += x0.w;
    s[4] += x1.x; s[5] += x1.y; s[6] += x1.z; s[7] += x1.w;
    if (f16out) {
      unsigned short w[8] = {f2b(x0.x), f2b(x0.y), f2b(x0.z), f2b(x0.w),
                             f2b(x1.x), f2b(x1.y), f2b(x1.z), f2b(x1.w)};
      const int ro = b * NR + r;
      *(s8v*)(f16out + (size_t)ro * VD + (d0 ^ (Frow(ro & 15) << 3))) = *(const s8v*)w;
    }
  }
  unsigned short w[8];
#pragma unroll
  for (int e = 0; e < 8; ++e) w[e] = f2b(s[e] * (1.f / NR));
  *(s8v*)(fm16 + (size_t)b * KFM + (d0 ^ (Frow(b & 15) << 3))) = *(const s8v*)w;
}

// FMG = b_v + sum_z GP[z]
__global__ void fmg_red_k(const float* __restrict__ gp, const float* __restrict__ bv,
                          float* __restrict__ fmg)
{
  const int idx = blockIdx.x * 256 + threadIdx.x;   // NB*H4
  if (idx >= NB * H4) return;
  float s = bv[idx & (H4 - 1)];
#pragma unroll
  for (int z = 0; z < ZFM; ++z) s += gp[(size_t)z * NB * H4 + idx];
  fmg[idx] = s;
}

// VINP = b_vin + sum_z GP[z] (N=NVI partials, keep n<IND)
__global__ void vinp_red_k(const float* __restrict__ gp, const float* __restrict__ bvin,
                           float* __restrict__ vinp)
{
  const int idx = blockIdx.x * 256 + threadIdx.x;   // NB*IND
  if (idx >= NB * IND) return;
  const int n = idx % IND, b = idx / IND;
  float s = bvin[n];
#pragma unroll
  for (int z = 0; z < ZFM; ++z) s += gp[(size_t)z * NB * NVI + (size_t)b * NVI + n];
  vinp[idx] = s;
}

// X2: plain bf16-hi, swizzled by F(b); payload d<300
__global__ void build_x2_k(const int* __restrict__ cap, const float* __restrict__ emb,
                           const float* __restrict__ vinp, unsigned short* __restrict__ X2)
{
  const int idx = blockIdx.x * 256 + threadIdx.x;
  if (idx >= NB * NT * X2LD) return;
  const int c = idx % X2LD;
  const int bt = idx / X2LD;
  const int t = bt % NT, b = bt / NT;
  const int Fs = Frow(b & 15) << 3;
  unsigned short val = 0;
  if (c < IND) {
    const float v = (t == 0) ? vinp[b * IND + c]
                             : emb[(size_t)cap[b * (NT - 1) + (t - 1)] * IND + c];
    val = f2b(v);
  }
  X2[(size_t)bt * X2LD + (c ^ Fs)] = val;
}

__global__ void lstm_pw_v_k(const float* __restrict__ gp, const float* __restrict__ fmg,
                            float* __restrict__ cv,
                            unsigned short* __restrict__ A2c, unsigned short* __restrict__ A2v)
{
  const int idx = blockIdx.x * 256 + threadIdx.x;
  if (idx >= NB * NH) return;
  const int n = idx & (NH - 1), b = idx >> 10;
  const size_t base = (size_t)b * H4;
  float gi = fmg[base + n], gf = fmg[base + NH + n];
  float gg = fmg[base + 2 * NH + n], go = fmg[base + 3 * NH + n];
#pragma unroll
  for (int z = 0; z < ZGV; ++z) {
    const float* g = gp + (size_t)z * NB * H4 + base;
    gi += g[n]; gf += g[NH + n]; gg += g[2 * NH + n]; go += g[3 * NH + n];
  }
  const float c2 = sigm(gf) * cv[idx] + sigm(gi) * tanhf(gg);
  const float h2 = sigm(go) * tanhf(c2);
  cv[idx] = c2;
  const int Fs = Frow(b & 15) << 3;
  store1(A2c + (size_t)b * KGC, 2048 + n, h2, Fs);
  store1(A2v + (size_t)b * A2VLD, 1024 + n, h2, Fs);
}

__global__ void lstm_pw_c_k(const float* __restrict__ gp, const float* __restrict__ bc,
                            float* __restrict__ cc,
                            unsigned short* __restrict__ A2v, unsigned short* __restrict__ A2c,
                            unsigned short* __restrict__ outh2, int t)
{
  const int idx = blockIdx.x * 256 + threadIdx.x;
  if (idx >= NB * NH) return;
  const int n = idx & (NH - 1), b = idx >> 10;
  const size_t base = (size_t)b * H4;
  float gi = bc[n], gf = bc[NH + n], gg = bc[2 * NH + n], go = bc[3 * NH + n];
#pragma unroll
  for (int z = 0; z < ZGC; ++z) {
    const float* g = gp + (size_t)z * NB * H4 + base;
    gi += g[n]; gf += g[NH + n]; gg += g[2 * NH + n]; go += g[3 * NH + n];
  }
  const float c2 = sigm(gf) * cc[idx] + sigm(gi) * tanhf(gg);
  const float h2 = sigm(go) * tanhf(c2);
  cc[idx] = c2;
  const int Fs = Frow(b & 15) << 3;
  store1(A2v + (size_t)b * A2VLD, n, h2, Fs);
  store1(A2c + (size_t)b * KGC, 3072 + n, h2, Fs);
  const int ro = b * NT + t;
  store1(outh2 + (size_t)ro * KCL, n, h2, Frow(ro & 15) << 3);
}

// =================== fused attention: ha-reduce + logits + softmax + feat_hat ===
template<bool F16>
__global__ __launch_bounds__(512)
void att_fused_k(const unsigned short* __restrict__ va16,
                 const float* __restrict__ hap,   // [ZHA][NB][NH]
                 const float* __restrict__ bha,
                 const float* __restrict__ Wa, const float* __restrict__ ba,
                 const unsigned short* __restrict__ f16,
                 const float* __restrict__ f32,
                 unsigned short* __restrict__ A2c,
                 float* __restrict__ att_out, int t)
{
  const int b = blockIdx.x, tid = threadIdx.x;
  const int lane = tid & 63, wid = tid >> 6;
  __shared__ float ha_s[NH];
  __shared__ float wa_s[NH];
  __shared__ float red_s[128];
  __shared__ float fh_s[2][VD];

  for (int j = tid; j < NH; j += 512) {
    float s = bha[j];
#pragma unroll
    for (int z = 0; z < ZHA; ++z) s += hap[((size_t)z * NB + b) * NH + j];
    ha_s[j] = s;
    wa_s[j] = Wa[j];
  }
  __syncthreads();

  for (int r = wid; r < NR; r += 8) {
    const unsigned short* vrow = va16 + ((size_t)b * NR + r) * NH + lane * 16;
    float s = 0.f;
#pragma unroll
    for (int u = 0; u < 2; ++u) {
      const s8v v = *(const s8v*)(vrow + u * 8);
      const int j0 = lane * 16 + u * 8;
#pragma unroll
      for (int e = 0; e < 8; ++e)
        s += tanhf(b2f((unsigned short)v[e]) + ha_s[j0 + e]) * wa_s[j0 + e];
    }
    for (int o = 32; o; o >>= 1) s += __shfl_down(s, o);
    if (lane == 0) red_s[r] = s + ba[0];
  }
  __syncthreads();

  if (wid == 0) {
    float v0 = (lane < NR) ? red_s[lane] : -3.4e38f;
    float v1 = (lane + 64 < NR) ? red_s[lane + 64] : -3.4e38f;
    float m = fmaxf(v0, v1);
    for (int o = 32; o; o >>= 1) m = fmaxf(m, __shfl_xor(m, o));
    const float e0 = (lane < NR) ? expf(v0 - m) : 0.f;
    const float e1 = (lane + 64 < NR) ? expf(v1 - m) : 0.f;
    float s = e0 + e1;
    for (int o = 32; o; o >>= 1) s += __shfl_xor(s, o);
    const float inv = 1.f / s;
    if (lane < NR) red_s[lane] = e0 * inv;
    if (lane + 64 < NR) red_s[lane + 64] = e1 * inv;
  }
  __syncthreads();
  if (tid < NR) att_out[((size_t)b * NT + t) * NR + tid] = red_s[tid];

  // feat_hat: split rows across 2 thread-halves; 8 d's (16B) per thread
  const int half = tid >> 8;
  const int dd = (tid & 255) * 8;
  const int r0 = half * 50, r1 = r0 + 50;
  float fh8[8] = {};
  if constexpr (F16) {
    const unsigned short* fbase = f16 + (size_t)b * NR * VD;
    for (int r = r0; r < r1; ++r) {
      const int ro = b * NR + r;
      const s8v f = *(const s8v*)(fbase + (size_t)r * VD + (dd ^ (Frow(ro & 15) << 3)));
      const float a = red_s[r];
#pragma unroll
      for (int e = 0; e < 8; ++e) fh8[e] += a * b2f((unsigned short)f[e]);
    }
  } else {
    const float* fb = f32 + (size_t)b * NR * VD + dd;
    for (int r = r0; r < r1; ++r) {
      const float4 x0 = *(const float4*)(fb + (size_t)r * VD);
      const float4 x1 = *(const float4*)(fb + (size_t)r * VD + 4);
      const float a = red_s[r];
      fh8[0] += a * x0.x; fh8[1] += a * x0.y; fh8[2] += a * x0.z; fh8[3] += a * x0.w;
      fh8[4] += a * x1.x; fh8[5] += a * x1.y; fh8[6] += a * x1.z; fh8[7] += a * x1.w;
    }
  }
#pragma unroll
  for (int e = 0; e < 8; ++e) fh_s[half][dd + e] = fh8[e];
  __syncthreads();

  unsigned short* rowbase = A2c + (size_t)b * KGC;
  const int Fs = Frow(b & 15) << 3;
  const int d0 = tid * 4;
#pragma unroll
  for (int e = 0; e < 4; ++e) {
    const float v = (fh_s[0][d0 + e] + fh_s[1][d0 + e]) * (1.f / NR);
    store1(rowbase, d0 + e, v, Fs);
  }
}

inline void convB(hipStream_t st, const float* src, int srcld, int K, int N,
                  unsigned short* dst, int dstld, int coff)
{
  dim3 g((K + 31) / 32, (N + 31) / 32);
  convB_k<<<g, 256, 0, st>>>(src, srcld, K, N, dst, dstld, coff);
}

} // namespace

extern "C" void kernel_launch(void* const* d_in, const int* in_sizes, int n_in,
                              void* d_out, int out_size, void* d_ws, size_t ws_size,
                              hipStream_t stream)
{
  const int*   caption = (const int*)  d_in[0];
  const float* feat    = (const float*)d_in[1];
  const float* emb     = (const float*)d_in[2];
  const float* W_vin   = (const float*)d_in[3];
  const float* b_vin   = (const float*)d_in[4];
  const float* W_ih_v  = (const float*)d_in[5];
  const float* W_hh_v  = (const float*)d_in[6];
  const float* b_v     = (const float*)d_in[7];
  const float* W_va    = (const float*)d_in[8];
  const float* b_va    = (const float*)d_in[9];
  const float* W_ha    = (const float*)d_in[10];
  const float* b_ha    = (const float*)d_in[11];
  const float* W_a     = (const float*)d_in[12];
  const float* b_a     = (const float*)d_in[13];
  const float* W_ih_c  = (const float*)d_in[14];
  const float* W_hh_c  = (const float*)d_in[15];
  const float* b_c     = (const float*)d_in[16];
  const float* W_cls   = (const float*)d_in[17];
  const float* b_cls   = (const float*)d_in[18];

  float* out_repr = (float*)d_out;                       // [NB,NT,VOC]
  float* out_att  = out_repr + (size_t)NB * NT * VOC;    // [NB,NT,NR]

  char* cur = (char*)d_ws;
  auto take = [&](size_t bytes) { char* p = cur; cur += bytes; return p; };

  unsigned short* A2v  = (unsigned short*)take((size_t)NB * A2VLD * 2);      // 1MB
  unsigned short* A2c  = (unsigned short*)take((size_t)NB * KGC * 2);        // 2MB
  float* CV            = (float*)take((size_t)NB * NH * 4);
  float* CC            = (float*)take((size_t)NB * NH * 4);
  const size_t ZERO_BYTES = (size_t)NB * A2VLD * 2 + (size_t)NB * KGC * 2
                          + 2 * (size_t)NB * NH * 4;

  float* VINP          = (float*)take((size_t)NB * IND * 4);
  unsigned short* X2   = (unsigned short*)take((size_t)NB * NT * X2LD * 2);  // 3.3MB
  float* FMG           = (float*)take((size_t)NB * H4 * 4);
  unsigned short* FM16 = (unsigned short*)take((size_t)NB * KFM * 2);        // 1MB
  unsigned short* VA16 = (unsigned short*)take((size_t)NB * NR * NH * 2);    // 52MB
  float* GP            = (float*)take((size_t)8 * NB * H4 * 4);              // 33.5MB
  float* HAP           = (float*)take((size_t)ZHA * NB * NH * 4);            // 8.4MB
  unsigned short* OUTH2= (unsigned short*)take((size_t)NB * NT * KCL * 2);   // 10.5MB
  unsigned short* Wgv2t= (unsigned short*)take((size_t)H4 * KGV * 2);        // 19.4MB
  unsigned short* Wha2t= (unsigned short*)take((size_t)NH * KHA * 2);        // 2.1MB
  unsigned short* Wgc2t= (unsigned short*)take((size_t)H4 * KGC * 2);        // 33.5MB
  unsigned short* Wfmg = (unsigned short*)take((size_t)H4 * KFM * 2);        // 16.8MB
  unsigned short* WvinT= (unsigned short*)take((size_t)NVI * KFM * 2);       // 1.6MB
  unsigned short* Wcls2t=(unsigned short*)take((size_t)VOCP * KCL * 2);      // 20.7MB
  unsigned short* Wva16t=(unsigned short*)take((size_t)NH * VD * 2);         // 4.2MB
  unsigned short* FEAT16=(unsigned short*)cur;                               // 105MB optional
  const bool useF16 = ((size_t)(cur - (char*)d_ws) + (size_t)NB * NR * VD * 2) <= ws_size;

  hipMemsetAsync(A2v, 0, ZERO_BYTES, stream);

  // ---- weight conversions (all swizzled bf16-hi) ----
  convB(stream, W_ih_v + (size_t)2048 * H4, H4, 1024, H4, Wgv2t, KGV, 0);
  convB(stream, W_hh_v,                     H4, 1024, H4, Wgv2t, KGV, 1024);
  convB(stream, W_ih_v + (size_t)3072 * H4, H4, 300,  H4, Wgv2t, KGV, 2048);
  zpad_swz_k<<<((H4 * (KGV - 2348)) + 255) / 256, 256, 0, stream>>>(
      Wgv2t, KGV, 2348, H4);
  convB(stream, W_ha, NH, 1024, NH, Wha2t, KHA, 0);
  convB(stream, W_ih_c,                     H4, 2048, H4, Wgc2t, KGC, 0);
  convB(stream, W_ih_c + (size_t)2048 * H4, H4, 1024, H4, Wgc2t, KGC, 2048);
  convB(stream, W_hh_c,                     H4, 1024, H4, Wgc2t, KGC, 3072);
  convB(stream, W_ih_v,                     H4, 2048, H4, Wfmg,  KFM, 0);
  convB(stream, W_vin, IND, 2048, IND, WvinT, KFM, 0);
  zfill_k<<<(((NVI - IND) * KFM) + 255) / 256, 256, 0, stream>>>(
      WvinT + (size_t)IND * KFM, (NVI - IND) * KFM);
  convB(stream, W_cls, VOC, 1024, VOC, Wcls2t, KCL, 0);
  zfill_k<<<(((VOCP - VOC) * KCL) + 255) / 256, 256, 0, stream>>>(
      Wcls2t + (size_t)VOC * KCL, (VOCP - VOC) * KCL);
  convB(stream, W_va, NH, VD, NH, Wva16t, VD, 0);

  // ---- setup ----
  feat_pass_k<<<(NB * (VD / 8) + 255) / 256, 256, 0, stream>>>(
      feat, FM16, useF16 ? FEAT16 : nullptr);
  gemm_sk2<false, 128, 128><<<dim3(NVI / 128, 2, ZFM), 256, 0, stream>>>(
      FM16, KFM, nullptr, 0, WvinT, KFM, GP, NVI, KFM, KSF);
  vinp_red_k<<<(NB * IND + 255) / 256, 256, 0, stream>>>(GP, b_vin, VINP);
  build_x2_k<<<(NB * NT * X2LD + 255) / 256, 256, 0, stream>>>(caption, emb, VINP, X2);
  gemm_sk2<false, 128, 128><<<dim3(H4 / 128, 2, ZFM), 256, 0, stream>>>(
      FM16, KFM, nullptr, 0, Wfmg, KFM, GP, H4, KFM, KSF);
  fmg_red_k<<<(NB * H4 + 255) / 256, 256, 0, stream>>>(GP, b_v, FMG);
  if (useF16) {
    dim3 g((NB * NR) / 128, NH / 128);
    gemm128<true><<<g, 256, 0, stream>>>(
        FEAT16, VD, Wva16t, VD, VA16, NH, b_va, NH, VD);
  } else {
    dim3 g((NB * NR) / 128, NH / 128);
    gemm_va_f32<<<g, 256, 0, stream>>>(feat, VD, Wva16t, VD, VA16, NH, b_va, NH, VD);
  }

  // ---- sequential decode (R17 best-measured launch geometry) ----
  for (int t = 0; t < NT; ++t) {
    gemm_sk2<true, 128, 64><<<dim3(H4 / 64, 2, ZGV), 256, 0, stream>>>(
        A2v, A2VLD, X2, t, Wgv2t, KGV, GP, H4, KGV, KSV);
    lstm_pw_v_k<<<(NB * NH + 255) / 256, 256, 0, stream>>>(GP, FMG, CV, A2c, A2v);
    gemm_sk2<false, 128, 64><<<dim3(NH / 64, 2, ZHA), 256, 0, stream>>>(
        A2c + 2048, KGC, nullptr, 0, Wha2t, KHA, HAP, NH, KHA, KSH);
    if (useF16)
      att_fused_k<true><<<NB, 512, 0, stream>>>(
          VA16, HAP, b_ha, W_a, b_a, FEAT16, nullptr, A2c, out_att, t);
    else
      att_fused_k<false><<<NB, 512, 0, stream>>>(
          VA16, HAP, b_ha, W_a, b_a, nullptr, feat, A2c, out_att, t);
    gemm_sk2<false, 128, 64><<<dim3(H4 / 64, 2, ZGC), 256, 0, stream>>>(
        A2c, KGC, nullptr, 0, Wgc2t, KGC, GP, H4, KGC, KSC);
    lstm_pw_c_k<<<(NB * NH + 255) / 256, 256, 0, stream>>>(GP, b_c, CC, A2v, A2c, OUTH2, t);
  }

  // ---- classifier: 128x128 tiles, plain bf16 both sides, K=1024 ----
  {
    dim3 g((NB * NT) / 128, VOCP / 128);
    gemm128<false><<<g, 256, 0, stream>>>(
        OUTH2, KCL, Wcls2t, KCL, out_repr, VOC, b_cls, VOC, KCL);
  }
}